// Round 7
// baseline (172.718 us; speedup 1.0000x reference)
//
#include <hip/hip_runtime.h>

// GAE + FiLM fused pipeline, f32, memory-bound.
// Dims fixed by setup_inputs(): N=2e6 (from in_sizes), Z=32, H=64, B=1024.
#define ZDIM 32
#define HDIM 64
#define BGRAPH 1024
#define SEGSTRIDE 33     // [denom | 32 x weighted-sum] per segment

typedef float f4 __attribute__((ext_vector_type(4)));
typedef unsigned short u16x4 __attribute__((ext_vector_type(4))); // 8B bf16 quad

// f32 -> bf16 round-to-nearest-even (inputs are finite normals)
__device__ __forceinline__ unsigned short f2bf(float f) {
    unsigned int u = __float_as_uint(f);
    return (unsigned short)((u + 0x7FFFu + ((u >> 16) & 1u)) >> 16);
}
__device__ __forceinline__ float bf2f(unsigned short h) {
    return __uint_as_float(((unsigned int)h) << 16);
}

// ---------------------------------------------------------------------------
// Segmented wave flush (stride-8 scan; batch_vec sorted -> keys contiguous).
// Last 8-lane group of each run commits with 8-lane-parallel atomics.
// ---------------------------------------------------------------------------
__device__ __forceinline__ void wave_flush_t(f4& acc, float& acc_e, int key,
                                             float* __restrict__ segacc,
                                             int lane, int q)
{
#pragma unroll
    for (int d = 8; d < 64; d <<= 1) {
        int   ku = __shfl_up(key, d);
        bool take = (lane >= d) && (ku == key);
        float ex = __shfl_up(acc_e, d);
        float vx = __shfl_up(acc.x, d);
        float vy = __shfl_up(acc.y, d);
        float vz = __shfl_up(acc.z, d);
        float vw = __shfl_up(acc.w, d);
        if (take) {
            acc_e += ex;
            acc.x += vx; acc.y += vy; acc.z += vz; acc.w += vw;
        }
    }
    int  kd   = __shfl_down(key, 8);
    bool last = (lane >= 56) || (kd != key);
    if (last && key >= 0) {
        float* dst = &segacc[key * SEGSTRIDE + 1 + q * 4];
        atomicAdd(dst + 0, acc.x);
        atomicAdd(dst + 1, acc.y);
        atomicAdd(dst + 2, acc.z);
        atomicAdd(dst + 3, acc.w);
        if (q == 0) atomicAdd(&segacc[key * SEGSTRIDE], acc_e);
    }
    acc_e = 0.f;
    acc.x = acc.y = acc.z = acc.w = 0.f;
}

#define GA_ITER 8   // float4s per thread; block covers 2048 f4 = 256 nodes

// ---------------------------------------------------------------------------
// Pass 1: gate dot (8-lane shfl reduce) + exp + segment accumulation, plus a
// bf16 copy of z written to z16 (halves film's read stream). ALL accesses
// plain — NT hints measured harmful (NT load: +11us on film R3->R4) or
// useless (MALL retention ~0% across R4/R5/R6 A/Bs).
// ---------------------------------------------------------------------------
template<bool W16>
__global__ __launch_bounds__(256) void k_gate_acc(
    const float* __restrict__ z, const int* __restrict__ bvec,
    const float* __restrict__ Wg, const float* __restrict__ bgp,
    float* __restrict__ segacc, u16x4* __restrict__ z16, int N)
{
    const int tid  = threadIdx.x;
    const int lane = tid & 63;
    const int q    = tid & 7;           // float4 slot within the node
    const long NF4 = (long)N * 8;
    const long base = (long)blockIdx.x * (256 * GA_ITER);

    const f4* z4  = (const f4*)z;
    const f4  wgq = ((const f4*)Wg)[q];
    const float bg0 = bgp[0];

    f4 acc; acc.x = acc.y = acc.z = acc.w = 0.f;
    float acc_e = 0.f;
    int   cur_b = -1;

    for (int i = 0; i < GA_ITER; ++i) {
        const long idx   = base + i * 256 + tid;
        const bool valid = (idx < NF4);
        f4 zz; zz.x = zz.y = zz.z = zz.w = 0.f;
        int b_new = cur_b;
        if (valid) {
            zz    = z4[idx];                       // plain load
            b_new = bvec[(int)(idx >> 3)];
            if (W16) {
                u16x4 h;
                h.x = f2bf(zz.x); h.y = f2bf(zz.y);
                h.z = f2bf(zz.z); h.w = f2bf(zz.w);
                z16[idx] = h;                      // plain store
            }
        }
        // gate partial dot + 8-lane reduce
        float p = zz.x * wgq.x + zz.y * wgq.y + zz.z * wgq.z + zz.w * wgq.w;
        p += __shfl_xor(p, 1);
        p += __shfl_xor(p, 2);
        p += __shfl_xor(p, 4);
        const float e = __expf(p + bg0);

        const bool need = valid && (cur_b >= 0) && (b_new != cur_b);
        if (__any(need))
            wave_flush_t(acc, acc_e, cur_b, segacc, lane, q);
        cur_b = b_new;
        if (valid) {
            acc.x = fmaf(e, zz.x, acc.x);
            acc.y = fmaf(e, zz.y, acc.y);
            acc.z = fmaf(e, zz.z, acc.z);
            acc.w = fmaf(e, zz.w, acc.w);
            if (q == 0) acc_e += e;
        }
    }
    wave_flush_t(acc, acc_e, cur_b, segacc, lane, q);
}

// ---------------------------------------------------------------------------
// Pass 2 (tiny): g = gsum/denom; write g; h = relu(g@W1+b1); gb = h@W2+b2;
// store [1+gamma | beta].
// ---------------------------------------------------------------------------
__global__ __launch_bounds__(64) void k_mlp(
    const float* __restrict__ segacc,
    const float* __restrict__ W1, const float* __restrict__ b1,
    const float* __restrict__ W2, const float* __restrict__ b2,
    float* __restrict__ g_out, float* __restrict__ fb)
{
    __shared__ float gsh[ZDIM];
    __shared__ float hsh[HDIM];
    const int b = blockIdx.x;
    const int t = threadIdx.x;

    if (t < ZDIM) {
        float d  = segacc[b * SEGSTRIDE];
        float v  = segacc[b * SEGSTRIDE + 1 + t];
        float gv = (d > 0.f) ? (v / d) : 0.f;
        gsh[t] = gv;
        g_out[b * ZDIM + t] = gv;
    }
    __syncthreads();

    float hv = b1[t];
#pragma unroll
    for (int k = 0; k < ZDIM; ++k) hv = fmaf(gsh[k], W1[k * HDIM + t], hv);
    hsh[t] = fmaxf(hv, 0.f);
    __syncthreads();

    float o = b2[t];
#pragma unroll
    for (int h = 0; h < HDIM; ++h) o = fmaf(hsh[h], W2[h * (2 * ZDIM) + t], o);
    fb[b * 64 + t] = (t < ZDIM) ? (1.0f + o) : o;   // gamma stored as (1+gamma)
}

#define KF_ITER 4

// ---------------------------------------------------------------------------
// Pass 3 (bf16 path): z_mod = bf16(z)*(1+gamma)[b] + beta[b]. Reads the
// 128 MB z16 copy; PLAIN stores (fill-kernel evidence: plain stores hit
// 7.1 TB/s; NT's no-evict rationale is dead since MALL retention is ~0%).
// bf16 error <= |z|*2^-9 ~ 0.011 abs, far under the 0.129 threshold.
// ---------------------------------------------------------------------------
__global__ __launch_bounds__(256) void k_film_bf16(
    const u16x4* __restrict__ z16, const int* __restrict__ bvec,
    const float* __restrict__ fb, float* __restrict__ out, long NF4)
{
    const long base = (long)blockIdx.x * (256 * KF_ITER) + threadIdx.x;
    const f4* fb4 = (const f4*)fb;

#pragma unroll
    for (int i = 0; i < KF_ITER; ++i) {
        const long idx = base + i * 256;
        if (idx >= NF4) return;
        const int n = (int)(idx >> 3);
        const int q = (int)(idx & 7);
        const int b = bvec[n];

        u16x4 h = z16[idx];
        f4 zz;
        zz.x = bf2f(h.x); zz.y = bf2f(h.y); zz.z = bf2f(h.z); zz.w = bf2f(h.w);
        f4 ga = fb4[b * 16 + q];        // (1+gamma) slice
        f4 be = fb4[b * 16 + 8 + q];    // beta slice
        f4 r;
        r.x = fmaf(zz.x, ga.x, be.x);
        r.y = fmaf(zz.y, ga.y, be.y);
        r.z = fmaf(zz.z, ga.z, be.z);
        r.w = fmaf(zz.w, ga.w, be.w);
        ((f4*)out)[idx] = r;            // plain store
    }
}

// Fallback pass 3 (f32 path), used only if d_ws is too small for z16.
__global__ __launch_bounds__(256) void k_film_f32(
    const float* __restrict__ z, const int* __restrict__ bvec,
    const float* __restrict__ fb, float* __restrict__ out, long NF4)
{
    const long base = (long)blockIdx.x * (256 * KF_ITER) + threadIdx.x;
    const f4* z4  = (const f4*)z;
    const f4* fb4 = (const f4*)fb;

#pragma unroll
    for (int i = 0; i < KF_ITER; ++i) {
        const long idx = base + i * 256;
        if (idx >= NF4) return;
        const int n = (int)(idx >> 3);
        const int q = (int)(idx & 7);
        const int b = bvec[n];

        f4 zz = z4[idx];
        f4 ga = fb4[b * 16 + q];
        f4 be = fb4[b * 16 + 8 + q];
        f4 r;
        r.x = fmaf(zz.x, ga.x, be.x);
        r.y = fmaf(zz.y, ga.y, be.y);
        r.z = fmaf(zz.z, ga.z, be.z);
        r.w = fmaf(zz.w, ga.w, be.w);
        ((f4*)out)[idx] = r;
    }
}

// ---------------------------------------------------------------------------
extern "C" void kernel_launch(void* const* d_in, const int* in_sizes, int n_in,
                              void* d_out, int out_size, void* d_ws, size_t ws_size,
                              hipStream_t stream) {
    const float* z    = (const float*)d_in[0];
    const float* Wg   = (const float*)d_in[1];
    const float* bg   = (const float*)d_in[2];
    const float* W1   = (const float*)d_in[3];
    const float* b1   = (const float*)d_in[4];
    const float* W2   = (const float*)d_in[5];
    const float* b2   = (const float*)d_in[6];
    const int*   bvec = (const int*)d_in[7];
    const int N = in_sizes[7];
    const int B = BGRAPH;

    float* segacc = (float*)d_ws;                       // B*33 floats
    float* fb     = segacc + B * SEGSTRIDE;             // B*64 floats
    u16x4* z16    = (u16x4*)(fb + B * 64);              // N*8 bf16-quads
    float* out    = (float*)d_out;
    float* g_out  = out + (size_t)N * ZDIM;             // g goes after z_mod

    const size_t head_bytes = (size_t)B * (SEGSTRIDE + 64) * sizeof(float);
    const size_t z16_bytes  = (size_t)N * ZDIM * 2;     // bf16 copy of z
    const bool   use16      = (ws_size >= head_bytes + z16_bytes);

    (void)hipMemsetAsync(segacc, 0, (size_t)B * SEGSTRIDE * sizeof(float), stream);

    const long NF4   = (long)N * 8;
    const int  grid1 = (int)((NF4 + 256 * GA_ITER - 1) / (256 * GA_ITER));
    if (use16)
        k_gate_acc<true><<<grid1, 256, 0, stream>>>(z, bvec, Wg, bg, segacc, z16, N);
    else
        k_gate_acc<false><<<grid1, 256, 0, stream>>>(z, bvec, Wg, bg, segacc, z16, N);

    k_mlp<<<B, 64, 0, stream>>>(segacc, W1, b1, W2, b2, g_out, fb);

    const int grid3 = (int)((NF4 + 256 * KF_ITER - 1) / (256 * KF_ITER));
    if (use16)
        k_film_bf16<<<grid3, 256, 0, stream>>>(z16, bvec, fb, out, NF4);
    else
        k_film_f32<<<grid3, 256, 0, stream>>>(z, bvec, fb, out, NF4);
}

// Round 8
// 102.740 us; speedup vs baseline: 1.6811x; 1.6811x over previous
//
#include <hip/hip_runtime.h>

// GAE + FiLM, fully fused: one workgroup per graph segment.
// Dims fixed by setup_inputs(): N=2e6, Z=32, H=64, B=1024. batch_vec sorted.
#define ZDIM 32
#define HDIM 64
#define BGRAPH 1024
#define CAP 2030            // nodes cached in LDS (129,920 B dynamic; seg max ~2100, overflow spills to global)
#define NTHREADS 1024

typedef float f4 __attribute__((ext_vector_type(4)));
typedef unsigned short u16x4 __attribute__((ext_vector_type(4)));   // 8B bf16 quad

// f32 -> bf16 round-to-nearest-even (inputs are finite normals)
__device__ __forceinline__ unsigned short f2bf(float f) {
    unsigned int u = __float_as_uint(f);
    return (unsigned short)((u + 0x7FFFu + ((u >> 16) & 1u)) >> 16);
}
__device__ __forceinline__ float bf2f(unsigned short h) {
    return __uint_as_float(((unsigned int)h) << 16);
}

__device__ __forceinline__ int lowerb(const int* __restrict__ v, int n, int key) {
    int lo = 0, hi = n;
    while (lo < hi) { int mid = (lo + hi) >> 1; if (v[mid] < key) lo = mid + 1; else hi = mid; }
    return lo;
}

// ---------------------------------------------------------------------------
// Per block b:
//  phase 1: stream segment-b's z (f32, ONCE from HBM). 8 lanes per node:
//           partial gate dot + 3-step shfl_xor reduce; e = exp(gate);
//           accumulate e and e*z in registers; stash bf16 z in LDS.
//  reduce:  wave shfl_down folds the 8 node-groups; LDS f32 atomics fold waves.
//  phase 2: in-block MLP (first 64 threads): g = sum/denom; h = relu(g@W1+b1);
//           gb = h@W2+b2; fbsh = [1+gamma | beta]; g written to out tail.
//  phase 3: replay z from LDS (bf16; err <= |z|*2^-9 ~ 0.011 << 0.129 thresh),
//           z_mod = z*(1+gamma)+beta, NT store (NT stores measured worth
//           ~30us on the 256MB out stream: R6->R7 A/B).
// ---------------------------------------------------------------------------
__global__ __launch_bounds__(NTHREADS) void k_fused(
    const float* __restrict__ z, const int* __restrict__ bvec,
    const float* __restrict__ Wg, const float* __restrict__ bgp,
    const float* __restrict__ W1, const float* __restrict__ b1,
    const float* __restrict__ W2, const float* __restrict__ b2,
    float* __restrict__ out, float* __restrict__ g_out, int N)
{
    extern __shared__ u16x4 z16s[];                 // CAP*8 entries, 8B each
    __shared__ float accum[1 + ZDIM];               // [denom | weighted sums]
    __shared__ float gsh[ZDIM];
    __shared__ float hsh[HDIM];
    __shared__ __align__(16) float fbsh[2 * ZDIM];  // [1+gamma | beta]
    __shared__ int   seg[2];

    const int b    = blockIdx.x;
    const int tid  = threadIdx.x;
    const int lane = tid & 63;
    const int q    = tid & 7;                       // float4 slot within node

    if (tid < 1 + ZDIM) accum[tid] = 0.f;
    if (tid < 2)        seg[tid]   = lowerb(bvec, N, b + tid);
    __syncthreads();

    const int  s     = seg[0];
    const int  nf4   = (seg[1] - s) * 8;            // float4 count, multiple of 8
    const long base4 = (long)s * 8;

    const f4* z4  = (const f4*)z;
    const f4  wgq = ((const f4*)Wg)[q];
    const float bg0 = bgp[0];

    // ---- phase 1: gate + accumulate + LDS stash -------------------------
    f4 acc; acc.x = acc.y = acc.z = acc.w = 0.f;
    float acc_e = 0.f;

    for (int k = tid; k < nf4; k += NTHREADS) {     // 8-lane groups stay intact
        f4 zz = z4[base4 + k];
        if (k < CAP * 8) {
            u16x4 h;
            h.x = f2bf(zz.x); h.y = f2bf(zz.y); h.z = f2bf(zz.z); h.w = f2bf(zz.w);
            z16s[k] = h;
        }
        float p = zz.x * wgq.x + zz.y * wgq.y + zz.z * wgq.z + zz.w * wgq.w;
        p += __shfl_xor(p, 1);
        p += __shfl_xor(p, 2);
        p += __shfl_xor(p, 4);                      // all 8 lanes hold full dot
        const float e = __expf(p + bg0);
        acc.x = fmaf(e, zz.x, acc.x);
        acc.y = fmaf(e, zz.y, acc.y);
        acc.z = fmaf(e, zz.z, acc.z);
        acc.w = fmaf(e, zz.w, acc.w);
        if (q == 0) acc_e += e;
    }
#pragma unroll
    for (int d = 8; d < 64; d <<= 1) {              // fold 8 node-groups per wave
        acc.x += __shfl_down(acc.x, d);
        acc.y += __shfl_down(acc.y, d);
        acc.z += __shfl_down(acc.z, d);
        acc.w += __shfl_down(acc.w, d);
        acc_e += __shfl_down(acc_e, d);
    }
    if (lane < 8) {                                 // fold 16 waves via LDS atomics
        atomicAdd(&accum[1 + q * 4 + 0], acc.x);
        atomicAdd(&accum[1 + q * 4 + 1], acc.y);
        atomicAdd(&accum[1 + q * 4 + 2], acc.z);
        atomicAdd(&accum[1 + q * 4 + 3], acc.w);
        if (lane == 0) atomicAdd(&accum[0], acc_e);
    }
    __syncthreads();

    // ---- phase 2: in-block MLP ------------------------------------------
    if (tid < ZDIM) {
        const float dd = accum[0];
        const float gv = (dd > 0.f) ? accum[1 + tid] / dd : 0.f;
        gsh[tid] = gv;
        g_out[b * ZDIM + tid] = gv;
    }
    __syncthreads();
    if (tid < HDIM) {
        float hv = b1[tid];
#pragma unroll
        for (int k = 0; k < ZDIM; ++k) hv = fmaf(gsh[k], W1[k * HDIM + tid], hv);
        hsh[tid] = fmaxf(hv, 0.f);
    }
    __syncthreads();
    if (tid < 2 * ZDIM) {
        float o = b2[tid];
#pragma unroll
        for (int h = 0; h < HDIM; ++h) o = fmaf(hsh[h], W2[h * (2 * ZDIM) + tid], o);
        fbsh[tid] = (tid < ZDIM) ? 1.0f + o : o;    // gamma stored as (1+gamma)
    }
    __syncthreads();

    // ---- phase 3: FiLM from LDS, NT stores ------------------------------
    const f4 ga = ((const f4*)fbsh)[q];
    const f4 be = ((const f4*)fbsh)[8 + q];
    f4* out4 = (f4*)out;
    for (int k = tid; k < nf4; k += NTHREADS) {
        f4 zz;
        if (k < CAP * 8) {
            u16x4 h = z16s[k];
            zz.x = bf2f(h.x); zz.y = bf2f(h.y); zz.z = bf2f(h.z); zz.w = bf2f(h.w);
        } else {
            zz = z4[base4 + k];                     // rare spill: seg > CAP nodes
        }
        f4 r;
        r.x = fmaf(zz.x, ga.x, be.x);
        r.y = fmaf(zz.y, ga.y, be.y);
        r.z = fmaf(zz.z, ga.z, be.z);
        r.w = fmaf(zz.w, ga.w, be.w);
        __builtin_nontemporal_store(r, &out4[base4 + k]);
    }
}

// ---------------------------------------------------------------------------
extern "C" void kernel_launch(void* const* d_in, const int* in_sizes, int n_in,
                              void* d_out, int out_size, void* d_ws, size_t ws_size,
                              hipStream_t stream) {
    const float* z    = (const float*)d_in[0];
    const float* Wg   = (const float*)d_in[1];
    const float* bg   = (const float*)d_in[2];
    const float* W1   = (const float*)d_in[3];
    const float* b1   = (const float*)d_in[4];
    const float* W2   = (const float*)d_in[5];
    const float* b2   = (const float*)d_in[6];
    const int*   bvec = (const int*)d_in[7];
    const int N = in_sizes[7];

    float* out   = (float*)d_out;
    float* g_out = out + (size_t)N * ZDIM;          // g after z_mod

    const size_t lds_bytes = (size_t)CAP * 8 * sizeof(u16x4);   // 129,920 B
    k_fused<<<BGRAPH, NTHREADS, lds_bytes, stream>>>(
        z, bvec, Wg, bg, W1, b1, W2, b2, out, g_out, N);
}